// Round 18
// baseline (273.932 us; speedup 1.0000x reference)
//
#include <hip/hip_runtime.h>
#include <hip/hip_bf16.h>
#include <math.h>

#define NDIM 256
#define HDIM 32
#define SCB 512

typedef __attribute__((ext_vector_type(8))) short bf16x8;
typedef __attribute__((ext_vector_type(4))) float f32x4;
typedef __attribute__((ext_vector_type(2))) float f32x2;
typedef unsigned long long ull;

// ---------- bf16 helpers ----------
__device__ inline float bf2f(unsigned short u) {
  union { unsigned int i; float f; } c; c.i = ((unsigned int)u) << 16; return c.f;
}
__device__ inline unsigned short f2bf(float f) {
  union { float f; unsigned int i; } c; c.f = f;
  unsigned int x = c.i;
  unsigned int lsb = (x >> 16) & 1u;
  x += 0x7fffu + lsb;
  return (unsigned short)(x >> 16);
}
__device__ inline float4 ldbf4(const unsigned short* p) {
  ull raw = *(const ull*)p;
  float4 f;
  f.x = bf2f((unsigned short)(raw));
  f.y = bf2f((unsigned short)(raw >> 16));
  f.z = bf2f((unsigned short)(raw >> 32));
  f.w = bf2f((unsigned short)(raw >> 48));
  return f;
}
__device__ inline void stbf4(unsigned short* p, float4 v) {
  ull raw = (ull)f2bf(v.x) | ((ull)f2bf(v.y) << 16)
          | ((ull)f2bf(v.z) << 32) | ((ull)f2bf(v.w) << 48);
  *(ull*)p = raw;
}
__device__ inline ull pk4_bf16(float v0, float v1, float v2, float v3) {
  return (ull)f2bf(v0) | ((ull)f2bf(v1) << 16) | ((ull)f2bf(v2) << 32) | ((ull)f2bf(v3) << 48);
}

// ---------- fp8 e4m3 helpers ----------
__device__ inline unsigned char f2e4m3(float v) {
#if __has_builtin(__builtin_amdgcn_cvt_pk_fp8_f32)
  return (unsigned char)(__builtin_amdgcn_cvt_pk_fp8_f32(v, v, 0, false) & 0xff);
#else
  union { float f; unsigned int u; } c; c.f = v;
  unsigned char s = (unsigned char)((c.u >> 24) & 0x80);
  float a = fabsf(v);
  if (!(a < 448.f)) return (unsigned char)(s | 0x7e);
  if (a < 0.0009765625f) return s;
  int e = (int)((c.u >> 23) & 0xff) - 127;
  if (e < -6) {
    int q = (int)rintf(ldexpf(a, 9));
    if (q >= 8) return (unsigned char)(s | 0x08);
    return (unsigned char)(s | q);
  }
  int q = (int)rintf(ldexpf(a, 3 - e));
  if (q == 16) { e++; q = 8; }
  if (e > 8) return (unsigned char)(s | 0x7e);
  return (unsigned char)(s | ((e + 7) << 3) | (q - 8));
#endif
}
__device__ inline unsigned int pk4_e4m3(float v0, float v1, float v2, float v3) {
#if __has_builtin(__builtin_amdgcn_cvt_pk_fp8_f32)
  int w = __builtin_amdgcn_cvt_pk_fp8_f32(v0, v1, 0, false);
  w = __builtin_amdgcn_cvt_pk_fp8_f32(v2, v3, w, true);
  return (unsigned int)w;
#else
  return (unsigned int)f2e4m3(v0) | ((unsigned int)f2e4m3(v1) << 8)
       | ((unsigned int)f2e4m3(v2) << 16) | ((unsigned int)f2e4m3(v3) << 24);
#endif
}
template<bool HI>
__device__ inline f32x2 e4m3pk(unsigned int w) {
#if __has_builtin(__builtin_amdgcn_cvt_pk_f32_fp8)
  return __builtin_amdgcn_cvt_pk_f32_fp8((int)w, HI);
#else
  unsigned int h = HI ? (w >> 16) : w;
  f32x2 r;
  #pragma unroll
  for (int j = 0; j < 2; ++j) {
    unsigned char b = (unsigned char)(h >> (8 * j));
    int e = (b >> 3) & 0xf, mm = b & 7;
    float val = e ? ldexpf((float)(8 + mm), e - 10) : ldexpf((float)mm, -9);
    r[j] = (b & 0x80) ? -val : val;
  }
  return r;
#endif
}

// ---------- prep: xconv + weight prep ----------
__global__ void prep_k(
    const float* __restrict__ x, unsigned short* __restrict__ xb, int n8, int nbx,
    const float* __restrict__ Wqkv, unsigned short* __restrict__ wqkvt,
    const float* __restrict__ W1, unsigned short* __restrict__ wf,
    const float* __restrict__ W2, unsigned short* __restrict__ w2t,
    const float* __restrict__ Wout, const float* __restrict__ bout,
    const float* __restrict__ b1, float* __restrict__ bc)
{
  int b = blockIdx.x;
  int tid = threadIdx.x;
  if (b < nbx) {
    int i = b * 256 + tid;
    if (i < n8) {
      const float* p = x + (size_t)i * 8;
      float4 a = *(const float4*)p;
      float4 bv = *(const float4*)(p + 4);
      ull lo = (ull)f2bf(a.x) | ((ull)f2bf(a.y) << 16) | ((ull)f2bf(a.z) << 32) | ((ull)f2bf(a.w) << 48);
      ull hi = (ull)f2bf(bv.x) | ((ull)f2bf(bv.y) << 16) | ((ull)f2bf(bv.z) << 32) | ((ull)f2bf(bv.w) << 48);
      ull* d = (ull*)(xb + (size_t)i * 8);
      d[0] = lo; d[1] = hi;
    }
    return;
  }
  b -= nbx;
  int idx = b * 256 + tid;
  if (idx < 196608) {
    int j = idx >> 8, k = idx & 255;
    int seg = j >> 8, jj = j & 255;
    int h = jj >> 5, t = jj & 31;
    int orig = h * 96 + seg * 32 + t;
    wqkvt[(size_t)j * 256 + k] = f2bf(Wqkv[(size_t)k * 768 + orig]);
  } else if (idx < 262144) {
    int i2 = idx - 196608;
    int n = i2 >> 8, k = i2 & 255;
    wf[(size_t)n * 512 + k] = f2bf(W1[(size_t)k * 256 + n]);
  } else if (idx < 327680) {
    int i3 = idx - 262144;
    int n = i3 >> 8, k = i3 & 255;
    w2t[(size_t)n * 256 + k] = f2bf(W2[(size_t)k * 256 + n]);
  } else if (idx < 393216) {
    int i4 = idx - 327680;
    int a = i4 >> 8, n = i4 & 255;
    float s = 0.f;
    #pragma unroll 4
    for (int j = 0; j < 256; ++j)
      s += Wout[(size_t)a * 256 + j] * W1[(size_t)(256 + j) * 256 + n];
    wf[(size_t)n * 512 + 256 + a] = f2bf(s);
  } else if (idx < 393472) {
    int n = idx - 393216;
    float s = b1[n];
    for (int j = 0; j < 256; ++j)
      s += bout[j] * W1[(size_t)(256 + j) * 256 + n];
    bc[n] = s;
  }
}

// ---------- FUSED: 8-replica histogram + QKV MFMA GEMM ----------
__global__ __launch_bounds__(256, 4) void histqkv_k(
    const int* __restrict__ dstv, int* __restrict__ deg8,
    unsigned short* __restrict__ erank, int E, int Nn, int nhist,
    const unsigned short* __restrict__ A1, const unsigned short* __restrict__ Wt,
    const float* __restrict__ bias,
    unsigned short* __restrict__ Oq, unsigned char* __restrict__ Ok, unsigned char* __restrict__ Ov,
    int M)
{
  __shared__ char smem[32768];
  if (blockIdx.x < nhist) {
    int b = blockIdx.x;
    int e = b * 256 + threadIdx.x;
    if (e < E) {
      int rep = b & 7;
      int r = atomicAdd(&deg8[(size_t)rep * Nn + dstv[e]], 1);
      erank[e] = (unsigned short)r;
    }
    return;
  }
  unsigned short* As = (unsigned short*)smem;
  unsigned short* Bs = (unsigned short*)(smem + 16384);
  const int tid = threadIdx.x;
  const int lane = tid & 63;
  const int wid = tid >> 6;

  const int nwg = gridDim.x - nhist;
  const int bid = blockIdx.x - nhist;
  const int q8 = nwg >> 3, r8 = nwg & 7;
  const int xcd = bid & 7, idx8 = bid >> 3;
  const int swz = (xcd < r8 ? xcd * (q8 + 1) : r8 * (q8 + 1) + (xcd - r8) * q8) + idx8;
  const int nct = 6;
  const int bmt = swz / nct;
  const int bnt = swz - bmt * nct;
  const int bm = bmt * 128;
  const int bn = bnt * 128;

  const int wr = (wid >> 1) << 6;
  const int wc = (wid & 1) << 6;
  const int l15 = lane & 15, lhi = lane >> 4;
  const int srow = lane >> 3;
  const int ssl = (((lane & 7) ^ (lane >> 3)) << 3);

  f32x4 acc[4][4];
  #pragma unroll
  for (int i = 0; i < 4; ++i)
    #pragma unroll
    for (int j = 0; j < 4; ++j) acc[i][j] = (f32x4){0.f, 0.f, 0.f, 0.f};

  for (int k0 = 0; k0 < 256; k0 += 64) {
    #pragma unroll
    for (int t = 0; t < 4; ++t) {
      int qi = wid * 4 + t;
      const unsigned short* ga = A1 + (size_t)(bm + qi * 8 + srow) * 256 + k0 + ssl;
      __builtin_amdgcn_global_load_lds(
          (const __attribute__((address_space(1))) void*)ga,
          (__attribute__((address_space(3))) void*)&As[qi * 512], 16, 0, 0);
      const unsigned short* gb = Wt + (size_t)(bn + qi * 8 + srow) * 256 + k0 + ssl;
      __builtin_amdgcn_global_load_lds(
          (const __attribute__((address_space(1))) void*)gb,
          (__attribute__((address_space(3))) void*)&Bs[qi * 512], 16, 0, 0);
    }
    __syncthreads();
    #pragma unroll
    for (int kk = 0; kk < 64; kk += 32) {
      bf16x8 af[4], bfr[4];
      #pragma unroll
      for (int mi = 0; mi < 4; ++mi) {
        int rA = wr + mi * 16 + l15;
        af[mi] = *(const bf16x8*)&As[rA * 64 + ((((kk >> 3) + lhi) ^ (rA & 7)) << 3)];
      }
      #pragma unroll
      for (int ni = 0; ni < 4; ++ni) {
        int rB = wc + ni * 16 + l15;
        bfr[ni] = *(const bf16x8*)&Bs[rB * 64 + ((((kk >> 3) + lhi) ^ (rB & 7)) << 3)];
      }
      #pragma unroll
      for (int mi = 0; mi < 4; ++mi)
        #pragma unroll
        for (int ni = 0; ni < 4; ++ni)
          acc[mi][ni] = __builtin_amdgcn_mfma_f32_16x16x32_bf16(bfr[ni], af[mi], acc[mi][ni], 0, 0, 0);
    }
    __syncthreads();
  }

  const int seg = (bn + wc) >> 8;
  const int jjbase = (bn + wc) & 255;
  char* slabB = smem + wid * 8192;
  if (seg == 0) {
    #pragma unroll
    for (int ni = 0; ni < 4; ++ni) {
      int cl = ni * 16 + (lhi << 2);
      int jj = jjbase + cl;
      float4 bb = *(const float4*)&bias[(jj >> 5) * 96 + (jj & 31)];
      #pragma unroll
      for (int mi = 0; mi < 4; ++mi) {
        int rl = mi * 16 + l15;
        *(ull*)&slabB[rl * 128 + ((cl * 2) ^ ((rl & 7) << 4))] = pk4_bf16(
            acc[mi][ni][0] + bb.x, acc[mi][ni][1] + bb.y,
            acc[mi][ni][2] + bb.z, acc[mi][ni][3] + bb.w);
      }
    }
    asm volatile("s_waitcnt lgkmcnt(0)" ::: "memory");
    __builtin_amdgcn_sched_barrier(0);
    int rl0 = lane >> 3, co = (lane & 7) << 4;
    #pragma unroll
    for (int t = 0; t < 8; ++t) {
      int rl = t * 8 + rl0;
      int gr = bm + wr + rl;
      if (gr < M)
        *(float4*)&Oq[(size_t)gr * NDIM + jjbase + (co >> 1)] =
            *(float4*)&slabB[rl * 128 + (co ^ ((rl & 7) << 4))];
    }
  } else {
    unsigned char* dstp = (seg == 1) ? Ok : Ov;
    #pragma unroll
    for (int ni = 0; ni < 4; ++ni) {
      int cl = ni * 16 + (lhi << 2);
      int jj = jjbase + cl;
      float4 bb = *(const float4*)&bias[(jj >> 5) * 96 + seg * 32 + (jj & 31)];
      #pragma unroll
      for (int mi = 0; mi < 4; ++mi) {
        int rl = mi * 16 + l15;
        *(unsigned int*)&slabB[rl * 64 + (cl ^ ((rl & 3) << 4))] = pk4_e4m3(
            acc[mi][ni][0] + bb.x, acc[mi][ni][1] + bb.y,
            acc[mi][ni][2] + bb.z, acc[mi][ni][3] + bb.w);
      }
    }
    asm volatile("s_waitcnt lgkmcnt(0)" ::: "memory");
    __builtin_amdgcn_sched_barrier(0);
    int rl0 = lane >> 2, co = (lane & 3) << 4;
    #pragma unroll
    for (int t = 0; t < 4; ++t) {
      int rl = t * 16 + rl0;
      int gr = bm + wr + rl;
      if (gr < M)
        *(float4*)&dstp[(size_t)gr * NDIM + jjbase + co] =
            *(float4*)&slabB[rl * 64 + (co ^ ((rl & 3) << 4))];
    }
  }
}

// ---------- CSR scan over 8 replicas ----------
__global__ __launch_bounds__(SCB) void bsum_k(const int* __restrict__ deg8, int* __restrict__ bsum, int n) {
  int tid = threadIdx.x;
  int i = blockIdx.x * SCB + tid;
  int v = 0;
  if (i < n) {
    #pragma unroll
    for (int r = 0; r < 8; ++r) v += deg8[(size_t)r * n + i];
  }
  #pragma unroll
  for (int d = 1; d < 64; d <<= 1) v += __shfl_xor(v, d);
  __shared__ int wsum[8];
  if ((tid & 63) == 0) wsum[tid >> 6] = v;
  __syncthreads();
  if (tid == 0) {
    int s = 0;
    #pragma unroll
    for (int j = 0; j < 8; ++j) s += wsum[j];
    bsum[blockIdx.x] = s;
  }
}

__global__ __launch_bounds__(128) void bscan_k(int* __restrict__ bsum, int nb) {
  __shared__ int tmp[128];
  int tid = threadIdx.x;
  int v = (tid < nb) ? bsum[tid] : 0;
  tmp[tid] = v;
  __syncthreads();
  for (int d = 1; d < 128; d <<= 1) {
    int t = (tid >= d) ? tmp[tid - d] : 0;
    __syncthreads();
    tmp[tid] += t;
    __syncthreads();
  }
  if (tid < nb) bsum[tid] = tmp[tid];
}

__global__ __launch_bounds__(SCB) void offs_k(const int* __restrict__ deg8, const int* __restrict__ bsum,
                                              int* __restrict__ offs, int* __restrict__ rbase, int n) {
  int tid = threadIdx.x, lane = tid & 63, wid = tid >> 6;
  int b = blockIdx.x;
  int i = b * SCB + tid;
  int c[8];
  int v = 0;
  if (i < n) {
    #pragma unroll
    for (int r = 0; r < 8; ++r) { c[r] = deg8[(size_t)r * n + i]; v += c[r]; }
  } else {
    #pragma unroll
    for (int r = 0; r < 8; ++r) c[r] = 0;
  }
  int incl = v;
  #pragma unroll
  for (int d = 1; d < 64; d <<= 1) { int t = __shfl_up(incl, d); if (lane >= d) incl += t; }
  __shared__ int wsum[8];
  if (lane == 63) wsum[wid] = incl;
  __syncthreads();
  if (tid < 8) {
    int s = wsum[tid];
    #pragma unroll
    for (int d = 1; d < 8; d <<= 1) { int t = __shfl_up(s, d); if (tid >= d) s += t; }
    wsum[tid] = s;
  }
  __syncthreads();
  int base = (b > 0 ? bsum[b - 1] : 0) + (wid > 0 ? wsum[wid - 1] : 0);
  if (i < n) {
    int start = base + incl - v;
    offs[i] = start;
    int p = start;
    #pragma unroll
    for (int r = 0; r < 8; ++r) { rbase[(size_t)r * n + i] = p; p += c[r]; }
  }
  if (i == n - 1) offs[n] = base + incl;
}

// ---------- atomic-free scatter via replica bases ----------
__global__ void scatter2_k(const int* __restrict__ src, const int* __restrict__ dstv,
                           const int* __restrict__ rbase, const unsigned short* __restrict__ erank,
                           int* __restrict__ ssrc, int E, int Nn) {
  int e = blockIdx.x * 256 + threadIdx.x;
  if (e < E) {
    int rep = (e >> 8) & 7;
    ssrc[rbase[(size_t)rep * Nn + dstv[e]] + erank[e]] = src[e];
  }
}

// ---------- per-node softmax attention, fp8 K/V, fixed-shift ----------
__global__ __launch_bounds__(256) void attn_k(
    const unsigned short* Q,
    const unsigned char* __restrict__ K8,
    const unsigned char* __restrict__ V8,
    const int* __restrict__ offs,
    const int* __restrict__ ssrc,
    unsigned short* agg, int N)
{
  int n = blockIdx.x * 4 + (threadIdx.x >> 6);
  if (n >= N) return;
  int lane = threadIdx.x & 63;
  int col = lane << 2;
  const float scale = 0.17677669529663689f;
  float4 q4 = ldbf4(Q + (size_t)n * NDIM + col);
  q4.x *= scale; q4.y *= scale; q4.z *= scale; q4.w *= scale;
  int e0 = offs[n], e1 = offs[n + 1];
  float den = 0.f;
  float ax = 0.f, ay = 0.f, az = 0.f, aw = 0.f;
  int e = e0;
  for (; e + 8 <= e1; e += 8) {
    unsigned int kw[8], vw[8];
    #pragma unroll
    for (int j = 0; j < 8; ++j) {
      int s = ssrc[e + j];
      kw[j] = *(const unsigned int*)(K8 + (size_t)s * NDIM + col);
      vw[j] = *(const unsigned int*)(V8 + (size_t)s * NDIM + col);
    }
    float d[8];
    #pragma unroll
    for (int j = 0; j < 8; ++j) {
      f32x2 k01 = e4m3pk<false>(kw[j]);
      f32x2 k23 = e4m3pk<true>(kw[j]);
      d[j] = q4.x * k01[0] + q4.y * k01[1] + q4.z * k23[0] + q4.w * k23[1];
    }
    #pragma unroll
    for (int j = 0; j < 8; ++j) {
      d[j] += __shfl_xor(d[j], 1);
      d[j] += __shfl_xor(d[j], 2);
      d[j] += __shfl_xor(d[j], 4);
    }
    #pragma unroll
    for (int j = 0; j < 8; ++j) {
      float p = __expf(d[j]);
      den += p;
      f32x2 v01 = e4m3pk<false>(vw[j]);
      f32x2 v23 = e4m3pk<true>(vw[j]);
      ax += p * v01[0]; ay += p * v01[1];
      az += p * v23[0]; aw += p * v23[1];
    }
  }
  for (; e + 4 <= e1; e += 4) {
    unsigned int kw[4], vw[4];
    #pragma unroll
    for (int j = 0; j < 4; ++j) {
      int s = ssrc[e + j];
      kw[j] = *(const unsigned int*)(K8 + (size_t)s * NDIM + col);
      vw[j] = *(const unsigned int*)(V8 + (size_t)s * NDIM + col);
    }
    float d[4];
    #pragma unroll
    for (int j = 0; j < 4; ++j) {
      f32x2 k01 = e4m3pk<false>(kw[j]);
      f32x2 k23 = e4m3pk<true>(kw[j]);
      d[j] = q4.x * k01[0] + q4.y * k01[1] + q4.z * k23[0] + q4.w * k23[1];
    }
    #pragma unroll
    for (int j = 0; j < 4; ++j) {
      d[j] += __shfl_xor(d[j], 1);
      d[j] += __shfl_xor(d[j], 2);
      d[j] += __shfl_xor(d[j], 4);
    }
    #pragma unroll
    for (int j = 0; j < 4; ++j) {
      float p = __expf(d[j]);
      den += p;
      f32x2 v01 = e4m3pk<false>(vw[j]);
      f32x2 v23 = e4m3pk<true>(vw[j]);
      ax += p * v01[0]; ay += p * v01[1];
      az += p * v23[0]; aw += p * v23[1];
    }
  }
  for (; e < e1; ++e) {
    int s = ssrc[e];
    unsigned int kw = *(const unsigned int*)(K8 + (size_t)s * NDIM + col);
    unsigned int vw = *(const unsigned int*)(V8 + (size_t)s * NDIM + col);
    f32x2 k01 = e4m3pk<false>(kw);
    f32x2 k23 = e4m3pk<true>(kw);
    float d = q4.x * k01[0] + q4.y * k01[1] + q4.z * k23[0] + q4.w * k23[1];
    d += __shfl_xor(d, 1);
    d += __shfl_xor(d, 2);
    d += __shfl_xor(d, 4);
    float p = __expf(d);
    den += p;
    f32x2 v01 = e4m3pk<false>(vw);
    f32x2 v23 = e4m3pk<true>(vw);
    ax += p * v01[0]; ay += p * v01[1];
    az += p * v23[0]; aw += p * v23[1];
  }
  float inv = (den > 0.f) ? 1.f / den : 0.f;
  stbf4(agg + (size_t)n * NDIM + col, make_float4(ax * inv, ay * inv, az * inv, aw * inv));
}

// ---------- MFMA GEMM (EPI 0 = fp32, 2 = gelu+bf16), swizzled-slab coalesced epilogue ----------
// __launch_bounds__(256,5): 5 blocks/CU (LDS 5*32KB = 160KB exactly), +25% resident waves
// to fill the per-block vmcnt(0)+barrier drain stall. Only change vs R17.
template<int EPI>
__global__ __launch_bounds__(256, 5) void mgemm_k(
    const unsigned short* __restrict__ A1, const unsigned short* __restrict__ A2,
    const unsigned short* __restrict__ Wt, const float* __restrict__ bias,
    float* __restrict__ Cf, unsigned short* __restrict__ Cb,
    int M, int K1, int K, int Ncol, int ldb, int nct)
{
  __shared__ char smem[32768];
  unsigned short* As = (unsigned short*)smem;
  unsigned short* Bs = (unsigned short*)(smem + 16384);
  const int tid = threadIdx.x;
  const int lane = tid & 63;
  const int wid = tid >> 6;

  const int nwg = gridDim.x;
  const int q8 = nwg >> 3, r8 = nwg & 7;
  const int xcd = blockIdx.x & 7, idx8 = blockIdx.x >> 3;
  const int swz = (xcd < r8 ? xcd * (q8 + 1) : r8 * (q8 + 1) + (xcd - r8) * q8) + idx8;
  const int bmt = swz / nct;
  const int bnt = swz - bmt * nct;
  const int bm = bmt * 128;
  const int bn = bnt * 128;

  const int wr = (wid >> 1) << 6;
  const int wc = (wid & 1) << 6;
  const int l15 = lane & 15, lhi = lane >> 4;
  const int srow = lane >> 3;
  const int ssl = (((lane & 7) ^ (lane >> 3)) << 3);

  f32x4 acc[4][4];
  #pragma unroll
  for (int i = 0; i < 4; ++i)
    #pragma unroll
    for (int j = 0; j < 4; ++j) acc[i][j] = (f32x4){0.f, 0.f, 0.f, 0.f};

  for (int k0 = 0; k0 < K; k0 += 64) {
    const unsigned short* Ab;
    int ks;
    if (k0 < K1) { Ab = A1; ks = k0; } else { Ab = A2; ks = k0 - K1; }
    #pragma unroll
    for (int t = 0; t < 4; ++t) {
      int qi = wid * 4 + t;
      const unsigned short* ga = Ab + (size_t)(bm + qi * 8 + srow) * 256 + ks + ssl;
      __builtin_amdgcn_global_load_lds(
          (const __attribute__((address_space(1))) void*)ga,
          (__attribute__((address_space(3))) void*)&As[qi * 512], 16, 0, 0);
      const unsigned short* gb = Wt + (size_t)(bn + qi * 8 + srow) * ldb + k0 + ssl;
      __builtin_amdgcn_global_load_lds(
          (const __attribute__((address_space(1))) void*)gb,
          (__attribute__((address_space(3))) void*)&Bs[qi * 512], 16, 0, 0);
    }
    __syncthreads();
    #pragma unroll
    for (int kk = 0; kk < 64; kk += 32) {
      bf16x8 af[4], bfr[4];
      #pragma unroll
      for (int mi = 0; mi < 4; ++mi) {
        int rA = wr + mi * 16 + l15;
        af[mi] = *(const bf16x8*)&As[rA * 64 + ((((kk >> 3) + lhi) ^ (rA & 7)) << 3)];
      }
      #pragma unroll
      for (int ni = 0; ni < 4; ++ni) {
        int rB = wc + ni * 16 + l15;
        bfr[ni] = *(const bf16x8*)&Bs[rB * 64 + ((((kk >> 3) + lhi) ^ (rB & 7)) << 3)];
      }
      #pragma unroll
      for (int mi = 0; mi < 4; ++mi)
        #pragma unroll
        for (int ni = 0; ni < 4; ++ni)
          acc[mi][ni] = __builtin_amdgcn_mfma_f32_16x16x32_bf16(bfr[ni], af[mi], acc[mi][ni], 0, 0, 0);
    }
    __syncthreads();
  }

  char* slabB = smem + wid * 8192;
  if (EPI == 0) {
    #pragma unroll
    for (int half = 0; half < 2; ++half) {
      #pragma unroll
      for (int nj = 0; nj < 2; ++nj) {
        int ni = half * 2 + nj;
        int cl = nj * 16 + (lhi << 2);
        float4 bb = *(const float4*)&bias[bn + wc + half * 32 + cl];
        #pragma unroll
        for (int mi = 0; mi < 4; ++mi) {
          int rl = mi * 16 + l15;
          *(float4*)&slabB[rl * 128 + ((cl * 4) ^ ((rl & 7) << 4))] = make_float4(
              acc[mi][ni][0] + bb.x, acc[mi][ni][1] + bb.y,
              acc[mi][ni][2] + bb.z, acc[mi][ni][3] + bb.w);
        }
      }
      asm volatile("s_waitcnt lgkmcnt(0)" ::: "memory");
      __builtin_amdgcn_sched_barrier(0);
      int rl0 = lane >> 3, co = (lane & 7) << 4;
      #pragma unroll
      for (int t = 0; t < 8; ++t) {
        int rl = t * 8 + rl0;
        int gr = bm + wr + rl;
        if (gr < M)
          *(float4*)&Cf[(size_t)gr * Ncol + bn + wc + half * 32 + (co >> 2)] =
              *(float4*)&slabB[rl * 128 + (co ^ ((rl & 7) << 4))];
      }
      if (half == 0) {
        asm volatile("s_waitcnt lgkmcnt(0)" ::: "memory");
        __builtin_amdgcn_sched_barrier(0);
      }
    }
  } else {
    #pragma unroll
    for (int ni = 0; ni < 4; ++ni) {
      int cl = ni * 16 + (lhi << 2);
      float4 bb = *(const float4*)&bias[bn + wc + cl];
      #pragma unroll
      for (int mi = 0; mi < 4; ++mi) {
        int rl = mi * 16 + l15;
        float v0 = acc[mi][ni][0] + bb.x;
        float v1 = acc[mi][ni][1] + bb.y;
        float v2 = acc[mi][ni][2] + bb.z;
        float v3 = acc[mi][ni][3] + bb.w;
        v0 = 0.5f * v0 * (1.0f + erff(v0 * 0.70710678118654752f));
        v1 = 0.5f * v1 * (1.0f + erff(v1 * 0.70710678118654752f));
        v2 = 0.5f * v2 * (1.0f + erff(v2 * 0.70710678118654752f));
        v3 = 0.5f * v3 * (1.0f + erff(v3 * 0.70710678118654752f));
        *(ull*)&slabB[rl * 128 + ((cl * 2) ^ ((rl & 7) << 4))] = pk4_bf16(v0, v1, v2, v3);
      }
    }
    asm volatile("s_waitcnt lgkmcnt(0)" ::: "memory");
    __builtin_amdgcn_sched_barrier(0);
    int rl0 = lane >> 3, co = (lane & 7) << 4;
    #pragma unroll
    for (int t = 0; t < 8; ++t) {
      int rl = t * 8 + rl0;
      int gr = bm + wr + rl;
      if (gr < M)
        *(float4*)&Cb[(size_t)gr * Ncol + bn + wc + (co >> 1)] =
            *(float4*)&slabB[rl * 128 + (co ^ ((rl & 7) << 4))];
    }
  }
}

extern "C" void kernel_launch(void* const* d_in, const int* in_sizes, int n_in,
                              void* d_out, int out_size, void* d_ws, size_t ws_size,
                              hipStream_t stream) {
  (void)n_in; (void)out_size; (void)ws_size;
  const float* x    = (const float*)d_in[0];
  const int*   src  = (const int*)d_in[1];
  const int*   dst  = (const int*)d_in[2];
  const float* Wqkv = (const float*)d_in[3];
  const float* bqkv = (const float*)d_in[4];
  const float* Wout = (const float*)d_in[5];
  const float* bout = (const float*)d_in[6];
  const float* W1   = (const float*)d_in[7];
  const float* b1   = (const float*)d_in[8];
  const float* W2   = (const float*)d_in[9];
  const float* b2   = (const float*)d_in[10];
  float* out = (float*)d_out;

  const int N = in_sizes[0] / NDIM;   // 50000
  const int E = in_sizes[1];          // 800000
  const int Mp = (N + 127) & ~127;    // 50048
  const int nb = (N + SCB - 1) / SCB;

  char* ws = (char*)d_ws;
  size_t off = 0;
  auto alloc = [&](size_t bytes) -> char* {
    char* p = ws + off;
    off += (bytes + 255) & ~(size_t)255;
    return p;
  };
  unsigned short* xb   = (unsigned short*)alloc((size_t)Mp * NDIM * 2);
  unsigned short* Q    = (unsigned short*)alloc((size_t)Mp * NDIM * 2);
  unsigned short* Kb   = (unsigned short*)alloc((size_t)Mp * NDIM * 2);
  unsigned short* Vb   = (unsigned short*)alloc((size_t)Mp * NDIM * 2);
  unsigned short* wqkvt = (unsigned short*)alloc((size_t)768 * 256 * 2);
  unsigned short* wft   = (unsigned short*)alloc((size_t)256 * 512 * 2);
  unsigned short* w2t   = (unsigned short*)alloc((size_t)256 * 256 * 2);
  float*          bc    = (float*)alloc(256 * 4);
  int* deg8   = (int*)alloc((size_t)8 * N * 4);
  int* rbase  = (int*)alloc((size_t)8 * N * 4);
  int* offs   = (int*)alloc((size_t)(N + 1) * 4);
  unsigned short* erank = (unsigned short*)alloc((size_t)E * 2);
  int* ssrc   = (int*)alloc((size_t)E * 4);
  int* bsum   = (int*)alloc((size_t)nb * 4);

  unsigned char* K8 = (unsigned char*)Kb;
  unsigned char* V8 = (unsigned char*)Vb;
  unsigned short* agg = Q;    // attn writes in place over Q
  unsigned short* h1  = Kb;   // Kb dead after attn

  const int n8  = N * NDIM / 8;
  const int nbx = (n8 + 255) / 256;
  const int nbw = (393472 + 255) / 256;
  const int nsc = (E + 255) / 256;          // 3125
  const int mt  = Mp / 128;                 // 391

  hipMemsetAsync(deg8, 0, (size_t)8 * N * 4, stream);

  // prep: xconv + weight conversions
  prep_k<<<nbx + nbw, 256, 0, stream>>>(
      x, xb, n8, nbx, Wqkv, wqkvt, W1, wft, W2, w2t, Wout, bout, b1, bc);

  // FUSED: 8-replica histogram (atomic wall) overlapped with QKV GEMM
  histqkv_k<<<nsc + mt * 6, 256, 0, stream>>>(
      dst, deg8, erank, E, N, nsc,
      xb, wqkvt, bqkv, Q, K8, V8, N);

  // CSR scan + replica bases
  bsum_k<<<nb, SCB, 0, stream>>>(deg8, bsum, N);
  bscan_k<<<1, 128, 0, stream>>>(bsum, nb);
  offs_k<<<nb, SCB, 0, stream>>>(deg8, bsum, offs, rbase, N);

  // atomic-free scatter
  scatter2_k<<<nsc, 256, 0, stream>>>(src, dst, rbase, erank, ssrc, E, N);

  // edge-softmax aggregation (agg == Q in place)
  attn_k<<<(N + 3) / 4, 256, 0, stream>>>(Q, K8, V8, offs, ssrc, agg, N);

  // FUSED FFN-in: gelu(x@W1a + agg@(Wout@W1b) + bc) -> h1 (bf16)
  mgemm_k<2><<<mt * 2, 256, 0, stream>>>(
      xb, agg, wft, bc, nullptr, h1, N, 256, 512, 256, 512, 2);

  // h1 @ W2 + b2 -> out (fp32)
  mgemm_k<0><<<mt * 2, 256, 0, stream>>>(
      h1, nullptr, w2t, b2, out, nullptr, N, 256, 256, 256, 256, 2);
}

// Round 19
// 221.074 us; speedup vs baseline: 1.2391x; 1.2391x over previous
//
#include <hip/hip_runtime.h>
#include <hip/hip_bf16.h>
#include <math.h>

#define NDIM 256
#define HDIM 32
#define SCB 512

typedef __attribute__((ext_vector_type(8))) short bf16x8;
typedef __attribute__((ext_vector_type(4))) float f32x4;
typedef __attribute__((ext_vector_type(2))) float f32x2;
typedef unsigned long long ull;

// ---------- bf16 helpers ----------
__device__ inline float bf2f(unsigned short u) {
  union { unsigned int i; float f; } c; c.i = ((unsigned int)u) << 16; return c.f;
}
__device__ inline unsigned short f2bf(float f) {
  union { float f; unsigned int i; } c; c.f = f;
  unsigned int x = c.i;
  unsigned int lsb = (x >> 16) & 1u;
  x += 0x7fffu + lsb;
  return (unsigned short)(x >> 16);
}
__device__ inline float4 ldbf4(const unsigned short* p) {
  ull raw = *(const ull*)p;
  float4 f;
  f.x = bf2f((unsigned short)(raw));
  f.y = bf2f((unsigned short)(raw >> 16));
  f.z = bf2f((unsigned short)(raw >> 32));
  f.w = bf2f((unsigned short)(raw >> 48));
  return f;
}
__device__ inline void stbf4(unsigned short* p, float4 v) {
  ull raw = (ull)f2bf(v.x) | ((ull)f2bf(v.y) << 16)
          | ((ull)f2bf(v.z) << 32) | ((ull)f2bf(v.w) << 48);
  *(ull*)p = raw;
}
__device__ inline ull pk4_bf16(float v0, float v1, float v2, float v3) {
  return (ull)f2bf(v0) | ((ull)f2bf(v1) << 16) | ((ull)f2bf(v2) << 32) | ((ull)f2bf(v3) << 48);
}

// ---------- fp8 e4m3 helpers ----------
__device__ inline unsigned char f2e4m3(float v) {
#if __has_builtin(__builtin_amdgcn_cvt_pk_fp8_f32)
  return (unsigned char)(__builtin_amdgcn_cvt_pk_fp8_f32(v, v, 0, false) & 0xff);
#else
  union { float f; unsigned int u; } c; c.f = v;
  unsigned char s = (unsigned char)((c.u >> 24) & 0x80);
  float a = fabsf(v);
  if (!(a < 448.f)) return (unsigned char)(s | 0x7e);
  if (a < 0.0009765625f) return s;
  int e = (int)((c.u >> 23) & 0xff) - 127;
  if (e < -6) {
    int q = (int)rintf(ldexpf(a, 9));
    if (q >= 8) return (unsigned char)(s | 0x08);
    return (unsigned char)(s | q);
  }
  int q = (int)rintf(ldexpf(a, 3 - e));
  if (q == 16) { e++; q = 8; }
  if (e > 8) return (unsigned char)(s | 0x7e);
  return (unsigned char)(s | ((e + 7) << 3) | (q - 8));
#endif
}
__device__ inline unsigned int pk4_e4m3(float v0, float v1, float v2, float v3) {
#if __has_builtin(__builtin_amdgcn_cvt_pk_fp8_f32)
  int w = __builtin_amdgcn_cvt_pk_fp8_f32(v0, v1, 0, false);
  w = __builtin_amdgcn_cvt_pk_fp8_f32(v2, v3, w, true);
  return (unsigned int)w;
#else
  return (unsigned int)f2e4m3(v0) | ((unsigned int)f2e4m3(v1) << 8)
       | ((unsigned int)f2e4m3(v2) << 16) | ((unsigned int)f2e4m3(v3) << 24);
#endif
}
template<bool HI>
__device__ inline f32x2 e4m3pk(unsigned int w) {
#if __has_builtin(__builtin_amdgcn_cvt_pk_f32_fp8)
  return __builtin_amdgcn_cvt_pk_f32_fp8((int)w, HI);
#else
  unsigned int h = HI ? (w >> 16) : w;
  f32x2 r;
  #pragma unroll
  for (int j = 0; j < 2; ++j) {
    unsigned char b = (unsigned char)(h >> (8 * j));
    int e = (b >> 3) & 0xf, mm = b & 7;
    float val = e ? ldexpf((float)(8 + mm), e - 10) : ldexpf((float)mm, -9);
    r[j] = (b & 0x80) ? -val : val;
  }
  return r;
#endif
}

// ---------- prep: xconv + weight prep ----------
__global__ void prep_k(
    const float* __restrict__ x, unsigned short* __restrict__ xb, int n8, int nbx,
    const float* __restrict__ Wqkv, unsigned short* __restrict__ wqkvt,
    const float* __restrict__ W1, unsigned short* __restrict__ wf,
    const float* __restrict__ W2, unsigned short* __restrict__ w2t,
    const float* __restrict__ Wout, const float* __restrict__ bout,
    const float* __restrict__ b1, float* __restrict__ bc)
{
  int b = blockIdx.x;
  int tid = threadIdx.x;
  if (b < nbx) {
    int i = b * 256 + tid;
    if (i < n8) {
      const float* p = x + (size_t)i * 8;
      float4 a = *(const float4*)p;
      float4 bv = *(const float4*)(p + 4);
      ull lo = (ull)f2bf(a.x) | ((ull)f2bf(a.y) << 16) | ((ull)f2bf(a.z) << 32) | ((ull)f2bf(a.w) << 48);
      ull hi = (ull)f2bf(bv.x) | ((ull)f2bf(bv.y) << 16) | ((ull)f2bf(bv.z) << 32) | ((ull)f2bf(bv.w) << 48);
      ull* d = (ull*)(xb + (size_t)i * 8);
      d[0] = lo; d[1] = hi;
    }
    return;
  }
  b -= nbx;
  int idx = b * 256 + tid;
  if (idx < 196608) {
    int j = idx >> 8, k = idx & 255;
    int seg = j >> 8, jj = j & 255;
    int h = jj >> 5, t = jj & 31;
    int orig = h * 96 + seg * 32 + t;
    wqkvt[(size_t)j * 256 + k] = f2bf(Wqkv[(size_t)k * 768 + orig]);
  } else if (idx < 262144) {
    int i2 = idx - 196608;
    int n = i2 >> 8, k = i2 & 255;
    wf[(size_t)n * 512 + k] = f2bf(W1[(size_t)k * 256 + n]);
  } else if (idx < 327680) {
    int i3 = idx - 262144;
    int n = i3 >> 8, k = i3 & 255;
    w2t[(size_t)n * 256 + k] = f2bf(W2[(size_t)k * 256 + n]);
  } else if (idx < 393216) {
    int i4 = idx - 327680;
    int a = i4 >> 8, n = i4 & 255;
    float s = 0.f;
    #pragma unroll 4
    for (int j = 0; j < 256; ++j)
      s += Wout[(size_t)a * 256 + j] * W1[(size_t)(256 + j) * 256 + n];
    wf[(size_t)n * 512 + 256 + a] = f2bf(s);
  } else if (idx < 393472) {
    int n = idx - 393216;
    float s = b1[n];
    for (int j = 0; j < 256; ++j)
      s += bout[j] * W1[(size_t)(256 + j) * 256 + n];
    bc[n] = s;
  }
}

// ---------- FUSED: 8-replica histogram + QKV MFMA GEMM ----------
__global__ __launch_bounds__(256, 4) void histqkv_k(
    const int* __restrict__ dstv, int* __restrict__ deg8,
    unsigned short* __restrict__ erank, int E, int Nn, int nhist,
    const unsigned short* __restrict__ A1, const unsigned short* __restrict__ Wt,
    const float* __restrict__ bias,
    unsigned short* __restrict__ Oq, unsigned char* __restrict__ Ok, unsigned char* __restrict__ Ov,
    int M)
{
  __shared__ char smem[32768];
  if (blockIdx.x < nhist) {
    int b = blockIdx.x;
    int e = b * 256 + threadIdx.x;
    if (e < E) {
      int rep = b & 7;
      int r = atomicAdd(&deg8[(size_t)rep * Nn + dstv[e]], 1);
      erank[e] = (unsigned short)r;
    }
    return;
  }
  unsigned short* As = (unsigned short*)smem;
  unsigned short* Bs = (unsigned short*)(smem + 16384);
  const int tid = threadIdx.x;
  const int lane = tid & 63;
  const int wid = tid >> 6;

  const int nwg = gridDim.x - nhist;
  const int bid = blockIdx.x - nhist;
  const int q8 = nwg >> 3, r8 = nwg & 7;
  const int xcd = bid & 7, idx8 = bid >> 3;
  const int swz = (xcd < r8 ? xcd * (q8 + 1) : r8 * (q8 + 1) + (xcd - r8) * q8) + idx8;
  const int nct = 6;
  const int bmt = swz / nct;
  const int bnt = swz - bmt * nct;
  const int bm = bmt * 128;
  const int bn = bnt * 128;

  const int wr = (wid >> 1) << 6;
  const int wc = (wid & 1) << 6;
  const int l15 = lane & 15, lhi = lane >> 4;
  const int srow = lane >> 3;
  const int ssl = (((lane & 7) ^ (lane >> 3)) << 3);

  f32x4 acc[4][4];
  #pragma unroll
  for (int i = 0; i < 4; ++i)
    #pragma unroll
    for (int j = 0; j < 4; ++j) acc[i][j] = (f32x4){0.f, 0.f, 0.f, 0.f};

  for (int k0 = 0; k0 < 256; k0 += 64) {
    #pragma unroll
    for (int t = 0; t < 4; ++t) {
      int qi = wid * 4 + t;
      const unsigned short* ga = A1 + (size_t)(bm + qi * 8 + srow) * 256 + k0 + ssl;
      __builtin_amdgcn_global_load_lds(
          (const __attribute__((address_space(1))) void*)ga,
          (__attribute__((address_space(3))) void*)&As[qi * 512], 16, 0, 0);
      const unsigned short* gb = Wt + (size_t)(bn + qi * 8 + srow) * 256 + k0 + ssl;
      __builtin_amdgcn_global_load_lds(
          (const __attribute__((address_space(1))) void*)gb,
          (__attribute__((address_space(3))) void*)&Bs[qi * 512], 16, 0, 0);
    }
    __syncthreads();
    #pragma unroll
    for (int kk = 0; kk < 64; kk += 32) {
      bf16x8 af[4], bfr[4];
      #pragma unroll
      for (int mi = 0; mi < 4; ++mi) {
        int rA = wr + mi * 16 + l15;
        af[mi] = *(const bf16x8*)&As[rA * 64 + ((((kk >> 3) + lhi) ^ (rA & 7)) << 3)];
      }
      #pragma unroll
      for (int ni = 0; ni < 4; ++ni) {
        int rB = wc + ni * 16 + l15;
        bfr[ni] = *(const bf16x8*)&Bs[rB * 64 + ((((kk >> 3) + lhi) ^ (rB & 7)) << 3)];
      }
      #pragma unroll
      for (int mi = 0; mi < 4; ++mi)
        #pragma unroll
        for (int ni = 0; ni < 4; ++ni)
          acc[mi][ni] = __builtin_amdgcn_mfma_f32_16x16x32_bf16(bfr[ni], af[mi], acc[mi][ni], 0, 0, 0);
    }
    __syncthreads();
  }

  const int seg = (bn + wc) >> 8;
  const int jjbase = (bn + wc) & 255;
  char* slabB = smem + wid * 8192;
  if (seg == 0) {
    #pragma unroll
    for (int ni = 0; ni < 4; ++ni) {
      int cl = ni * 16 + (lhi << 2);
      int jj = jjbase + cl;
      float4 bb = *(const float4*)&bias[(jj >> 5) * 96 + (jj & 31)];
      #pragma unroll
      for (int mi = 0; mi < 4; ++mi) {
        int rl = mi * 16 + l15;
        *(ull*)&slabB[rl * 128 + ((cl * 2) ^ ((rl & 7) << 4))] = pk4_bf16(
            acc[mi][ni][0] + bb.x, acc[mi][ni][1] + bb.y,
            acc[mi][ni][2] + bb.z, acc[mi][ni][3] + bb.w);
      }
    }
    asm volatile("s_waitcnt lgkmcnt(0)" ::: "memory");
    __builtin_amdgcn_sched_barrier(0);
    int rl0 = lane >> 3, co = (lane & 7) << 4;
    #pragma unroll
    for (int t = 0; t < 8; ++t) {
      int rl = t * 8 + rl0;
      int gr = bm + wr + rl;
      if (gr < M)
        *(float4*)&Oq[(size_t)gr * NDIM + jjbase + (co >> 1)] =
            *(float4*)&slabB[rl * 128 + (co ^ ((rl & 7) << 4))];
    }
  } else {
    unsigned char* dstp = (seg == 1) ? Ok : Ov;
    #pragma unroll
    for (int ni = 0; ni < 4; ++ni) {
      int cl = ni * 16 + (lhi << 2);
      int jj = jjbase + cl;
      float4 bb = *(const float4*)&bias[(jj >> 5) * 96 + seg * 32 + (jj & 31)];
      #pragma unroll
      for (int mi = 0; mi < 4; ++mi) {
        int rl = mi * 16 + l15;
        *(unsigned int*)&slabB[rl * 64 + (cl ^ ((rl & 3) << 4))] = pk4_e4m3(
            acc[mi][ni][0] + bb.x, acc[mi][ni][1] + bb.y,
            acc[mi][ni][2] + bb.z, acc[mi][ni][3] + bb.w);
      }
    }
    asm volatile("s_waitcnt lgkmcnt(0)" ::: "memory");
    __builtin_amdgcn_sched_barrier(0);
    int rl0 = lane >> 2, co = (lane & 3) << 4;
    #pragma unroll
    for (int t = 0; t < 4; ++t) {
      int rl = t * 16 + rl0;
      int gr = bm + wr + rl;
      if (gr < M)
        *(float4*)&dstp[(size_t)gr * NDIM + jjbase + co] =
            *(float4*)&slabB[rl * 64 + (co ^ ((rl & 3) << 4))];
    }
  }
}

// ---------- CSR scan over 8 replicas ----------
__global__ __launch_bounds__(SCB) void bsum_k(const int* __restrict__ deg8, int* __restrict__ bsum, int n) {
  int tid = threadIdx.x;
  int i = blockIdx.x * SCB + tid;
  int v = 0;
  if (i < n) {
    #pragma unroll
    for (int r = 0; r < 8; ++r) v += deg8[(size_t)r * n + i];
  }
  #pragma unroll
  for (int d = 1; d < 64; d <<= 1) v += __shfl_xor(v, d);
  __shared__ int wsum[8];
  if ((tid & 63) == 0) wsum[tid >> 6] = v;
  __syncthreads();
  if (tid == 0) {
    int s = 0;
    #pragma unroll
    for (int j = 0; j < 8; ++j) s += wsum[j];
    bsum[blockIdx.x] = s;
  }
}

__global__ __launch_bounds__(128) void bscan_k(int* __restrict__ bsum, int nb) {
  __shared__ int tmp[128];
  int tid = threadIdx.x;
  int v = (tid < nb) ? bsum[tid] : 0;
  tmp[tid] = v;
  __syncthreads();
  for (int d = 1; d < 128; d <<= 1) {
    int t = (tid >= d) ? tmp[tid - d] : 0;
    __syncthreads();
    tmp[tid] += t;
    __syncthreads();
  }
  if (tid < nb) bsum[tid] = tmp[tid];
}

__global__ __launch_bounds__(SCB) void offs_k(const int* __restrict__ deg8, const int* __restrict__ bsum,
                                              int* __restrict__ offs, int* __restrict__ rbase, int n) {
  int tid = threadIdx.x, lane = tid & 63, wid = tid >> 6;
  int b = blockIdx.x;
  int i = b * SCB + tid;
  int c[8];
  int v = 0;
  if (i < n) {
    #pragma unroll
    for (int r = 0; r < 8; ++r) { c[r] = deg8[(size_t)r * n + i]; v += c[r]; }
  } else {
    #pragma unroll
    for (int r = 0; r < 8; ++r) c[r] = 0;
  }
  int incl = v;
  #pragma unroll
  for (int d = 1; d < 64; d <<= 1) { int t = __shfl_up(incl, d); if (lane >= d) incl += t; }
  __shared__ int wsum[8];
  if (lane == 63) wsum[wid] = incl;
  __syncthreads();
  if (tid < 8) {
    int s = wsum[tid];
    #pragma unroll
    for (int d = 1; d < 8; d <<= 1) { int t = __shfl_up(s, d); if (tid >= d) s += t; }
    wsum[tid] = s;
  }
  __syncthreads();
  int base = (b > 0 ? bsum[b - 1] : 0) + (wid > 0 ? wsum[wid - 1] : 0);
  if (i < n) {
    int start = base + incl - v;
    offs[i] = start;
    int p = start;
    #pragma unroll
    for (int r = 0; r < 8; ++r) { rbase[(size_t)r * n + i] = p; p += c[r]; }
  }
  if (i == n - 1) offs[n] = base + incl;
}

// ---------- atomic-free scatter via replica bases ----------
__global__ void scatter2_k(const int* __restrict__ src, const int* __restrict__ dstv,
                           const int* __restrict__ rbase, const unsigned short* __restrict__ erank,
                           int* __restrict__ ssrc, int E, int Nn) {
  int e = blockIdx.x * 256 + threadIdx.x;
  if (e < E) {
    int rep = (e >> 8) & 7;
    ssrc[rbase[(size_t)rep * Nn + dstv[e]] + erank[e]] = src[e];
  }
}

// ---------- per-node softmax attention, fp8 K/V, fixed-shift ----------
__global__ __launch_bounds__(256) void attn_k(
    const unsigned short* Q,
    const unsigned char* __restrict__ K8,
    const unsigned char* __restrict__ V8,
    const int* __restrict__ offs,
    const int* __restrict__ ssrc,
    unsigned short* agg, int N)
{
  int n = blockIdx.x * 4 + (threadIdx.x >> 6);
  if (n >= N) return;
  int lane = threadIdx.x & 63;
  int col = lane << 2;
  const float scale = 0.17677669529663689f;
  float4 q4 = ldbf4(Q + (size_t)n * NDIM + col);
  q4.x *= scale; q4.y *= scale; q4.z *= scale; q4.w *= scale;
  int e0 = offs[n], e1 = offs[n + 1];
  float den = 0.f;
  float ax = 0.f, ay = 0.f, az = 0.f, aw = 0.f;
  int e = e0;
  for (; e + 8 <= e1; e += 8) {
    unsigned int kw[8], vw[8];
    #pragma unroll
    for (int j = 0; j < 8; ++j) {
      int s = ssrc[e + j];
      kw[j] = *(const unsigned int*)(K8 + (size_t)s * NDIM + col);
      vw[j] = *(const unsigned int*)(V8 + (size_t)s * NDIM + col);
    }
    float d[8];
    #pragma unroll
    for (int j = 0; j < 8; ++j) {
      f32x2 k01 = e4m3pk<false>(kw[j]);
      f32x2 k23 = e4m3pk<true>(kw[j]);
      d[j] = q4.x * k01[0] + q4.y * k01[1] + q4.z * k23[0] + q4.w * k23[1];
    }
    #pragma unroll
    for (int j = 0; j < 8; ++j) {
      d[j] += __shfl_xor(d[j], 1);
      d[j] += __shfl_xor(d[j], 2);
      d[j] += __shfl_xor(d[j], 4);
    }
    #pragma unroll
    for (int j = 0; j < 8; ++j) {
      float p = __expf(d[j]);
      den += p;
      f32x2 v01 = e4m3pk<false>(vw[j]);
      f32x2 v23 = e4m3pk<true>(vw[j]);
      ax += p * v01[0]; ay += p * v01[1];
      az += p * v23[0]; aw += p * v23[1];
    }
  }
  for (; e + 4 <= e1; e += 4) {
    unsigned int kw[4], vw[4];
    #pragma unroll
    for (int j = 0; j < 4; ++j) {
      int s = ssrc[e + j];
      kw[j] = *(const unsigned int*)(K8 + (size_t)s * NDIM + col);
      vw[j] = *(const unsigned int*)(V8 + (size_t)s * NDIM + col);
    }
    float d[4];
    #pragma unroll
    for (int j = 0; j < 4; ++j) {
      f32x2 k01 = e4m3pk<false>(kw[j]);
      f32x2 k23 = e4m3pk<true>(kw[j]);
      d[j] = q4.x * k01[0] + q4.y * k01[1] + q4.z * k23[0] + q4.w * k23[1];
    }
    #pragma unroll
    for (int j = 0; j < 4; ++j) {
      d[j] += __shfl_xor(d[j], 1);
      d[j] += __shfl_xor(d[j], 2);
      d[j] += __shfl_xor(d[j], 4);
    }
    #pragma unroll
    for (int j = 0; j < 4; ++j) {
      float p = __expf(d[j]);
      den += p;
      f32x2 v01 = e4m3pk<false>(vw[j]);
      f32x2 v23 = e4m3pk<true>(vw[j]);
      ax += p * v01[0]; ay += p * v01[1];
      az += p * v23[0]; aw += p * v23[1];
    }
  }
  for (; e < e1; ++e) {
    int s = ssrc[e];
    unsigned int kw = *(const unsigned int*)(K8 + (size_t)s * NDIM + col);
    unsigned int vw = *(const unsigned int*)(V8 + (size_t)s * NDIM + col);
    f32x2 k01 = e4m3pk<false>(kw);
    f32x2 k23 = e4m3pk<true>(kw);
    float d = q4.x * k01[0] + q4.y * k01[1] + q4.z * k23[0] + q4.w * k23[1];
    d += __shfl_xor(d, 1);
    d += __shfl_xor(d, 2);
    d += __shfl_xor(d, 4);
    float p = __expf(d);
    den += p;
    f32x2 v01 = e4m3pk<false>(vw);
    f32x2 v23 = e4m3pk<true>(vw);
    ax += p * v01[0]; ay += p * v01[1];
    az += p * v23[0]; aw += p * v23[1];
  }
  float inv = (den > 0.f) ? 1.f / den : 0.f;
  stbf4(agg + (size_t)n * NDIM + col, make_float4(ax * inv, ay * inv, az * inv, aw * inv));
}

// ---------- MFMA GEMM (EPI 0 = fp32, 2 = gelu+bf16), swizzled-slab coalesced epilogue ----------
template<int EPI>
__global__ __launch_bounds__(256, 4) void mgemm_k(
    const unsigned short* __restrict__ A1, const unsigned short* __restrict__ A2,
    const unsigned short* __restrict__ Wt, const float* __restrict__ bias,
    float* __restrict__ Cf, unsigned short* __restrict__ Cb,
    int M, int K1, int K, int Ncol, int ldb, int nct)
{
  __shared__ char smem[32768];
  unsigned short* As = (unsigned short*)smem;
  unsigned short* Bs = (unsigned short*)(smem + 16384);
  const int tid = threadIdx.x;
  const int lane = tid & 63;
  const int wid = tid >> 6;

  const int nwg = gridDim.x;
  const int q8 = nwg >> 3, r8 = nwg & 7;
  const int xcd = blockIdx.x & 7, idx8 = blockIdx.x >> 3;
  const int swz = (xcd < r8 ? xcd * (q8 + 1) : r8 * (q8 + 1) + (xcd - r8) * q8) + idx8;
  const int bmt = swz / nct;
  const int bnt = swz - bmt * nct;
  const int bm = bmt * 128;
  const int bn = bnt * 128;

  const int wr = (wid >> 1) << 6;
  const int wc = (wid & 1) << 6;
  const int l15 = lane & 15, lhi = lane >> 4;
  const int srow = lane >> 3;
  const int ssl = (((lane & 7) ^ (lane >> 3)) << 3);

  f32x4 acc[4][4];
  #pragma unroll
  for (int i = 0; i < 4; ++i)
    #pragma unroll
    for (int j = 0; j < 4; ++j) acc[i][j] = (f32x4){0.f, 0.f, 0.f, 0.f};

  for (int k0 = 0; k0 < K; k0 += 64) {
    const unsigned short* Ab;
    int ks;
    if (k0 < K1) { Ab = A1; ks = k0; } else { Ab = A2; ks = k0 - K1; }
    #pragma unroll
    for (int t = 0; t < 4; ++t) {
      int qi = wid * 4 + t;
      const unsigned short* ga = Ab + (size_t)(bm + qi * 8 + srow) * 256 + ks + ssl;
      __builtin_amdgcn_global_load_lds(
          (const __attribute__((address_space(1))) void*)ga,
          (__attribute__((address_space(3))) void*)&As[qi * 512], 16, 0, 0);
      const unsigned short* gb = Wt + (size_t)(bn + qi * 8 + srow) * ldb + k0 + ssl;
      __builtin_amdgcn_global_load_lds(
          (const __attribute__((address_space(1))) void*)gb,
          (__attribute__((address_space(3))) void*)&Bs[qi * 512], 16, 0, 0);
    }
    __syncthreads();
    #pragma unroll
    for (int kk = 0; kk < 64; kk += 32) {
      bf16x8 af[4], bfr[4];
      #pragma unroll
      for (int mi = 0; mi < 4; ++mi) {
        int rA = wr + mi * 16 + l15;
        af[mi] = *(const bf16x8*)&As[rA * 64 + ((((kk >> 3) + lhi) ^ (rA & 7)) << 3)];
      }
      #pragma unroll
      for (int ni = 0; ni < 4; ++ni) {
        int rB = wc + ni * 16 + l15;
        bfr[ni] = *(const bf16x8*)&Bs[rB * 64 + ((((kk >> 3) + lhi) ^ (rB & 7)) << 3)];
      }
      #pragma unroll
      for (int mi = 0; mi < 4; ++mi)
        #pragma unroll
        for (int ni = 0; ni < 4; ++ni)
          acc[mi][ni] = __builtin_amdgcn_mfma_f32_16x16x32_bf16(bfr[ni], af[mi], acc[mi][ni], 0, 0, 0);
    }
    __syncthreads();
  }

  char* slabB = smem + wid * 8192;
  if (EPI == 0) {
    #pragma unroll
    for (int half = 0; half < 2; ++half) {
      #pragma unroll
      for (int nj = 0; nj < 2; ++nj) {
        int ni = half * 2 + nj;
        int cl = nj * 16 + (lhi << 2);
        float4 bb = *(const float4*)&bias[bn + wc + half * 32 + cl];
        #pragma unroll
        for (int mi = 0; mi < 4; ++mi) {
          int rl = mi * 16 + l15;
          *(float4*)&slabB[rl * 128 + ((cl * 4) ^ ((rl & 7) << 4))] = make_float4(
              acc[mi][ni][0] + bb.x, acc[mi][ni][1] + bb.y,
              acc[mi][ni][2] + bb.z, acc[mi][ni][3] + bb.w);
        }
      }
      asm volatile("s_waitcnt lgkmcnt(0)" ::: "memory");
      __builtin_amdgcn_sched_barrier(0);
      int rl0 = lane >> 3, co = (lane & 7) << 4;
      #pragma unroll
      for (int t = 0; t < 8; ++t) {
        int rl = t * 8 + rl0;
        int gr = bm + wr + rl;
        if (gr < M)
          *(float4*)&Cf[(size_t)gr * Ncol + bn + wc + half * 32 + (co >> 2)] =
              *(float4*)&slabB[rl * 128 + (co ^ ((rl & 7) << 4))];
      }
      if (half == 0) {
        asm volatile("s_waitcnt lgkmcnt(0)" ::: "memory");
        __builtin_amdgcn_sched_barrier(0);
      }
    }
  } else {
    #pragma unroll
    for (int ni = 0; ni < 4; ++ni) {
      int cl = ni * 16 + (lhi << 2);
      float4 bb = *(const float4*)&bias[bn + wc + cl];
      #pragma unroll
      for (int mi = 0; mi < 4; ++mi) {
        int rl = mi * 16 + l15;
        float v0 = acc[mi][ni][0] + bb.x;
        float v1 = acc[mi][ni][1] + bb.y;
        float v2 = acc[mi][ni][2] + bb.z;
        float v3 = acc[mi][ni][3] + bb.w;
        v0 = 0.5f * v0 * (1.0f + erff(v0 * 0.70710678118654752f));
        v1 = 0.5f * v1 * (1.0f + erff(v1 * 0.70710678118654752f));
        v2 = 0.5f * v2 * (1.0f + erff(v2 * 0.70710678118654752f));
        v3 = 0.5f * v3 * (1.0f + erff(v3 * 0.70710678118654752f));
        *(ull*)&slabB[rl * 128 + ((cl * 2) ^ ((rl & 7) << 4))] = pk4_bf16(v0, v1, v2, v3);
      }
    }
    asm volatile("s_waitcnt lgkmcnt(0)" ::: "memory");
    __builtin_amdgcn_sched_barrier(0);
    int rl0 = lane >> 3, co = (lane & 7) << 4;
    #pragma unroll
    for (int t = 0; t < 8; ++t) {
      int rl = t * 8 + rl0;
      int gr = bm + wr + rl;
      if (gr < M)
        *(float4*)&Cb[(size_t)gr * Ncol + bn + wc + (co >> 1)] =
            *(float4*)&slabB[rl * 128 + (co ^ ((rl & 7) << 4))];
    }
  }
}

extern "C" void kernel_launch(void* const* d_in, const int* in_sizes, int n_in,
                              void* d_out, int out_size, void* d_ws, size_t ws_size,
                              hipStream_t stream) {
  (void)n_in; (void)out_size; (void)ws_size;
  const float* x    = (const float*)d_in[0];
  const int*   src  = (const int*)d_in[1];
  const int*   dst  = (const int*)d_in[2];
  const float* Wqkv = (const float*)d_in[3];
  const float* bqkv = (const float*)d_in[4];
  const float* Wout = (const float*)d_in[5];
  const float* bout = (const float*)d_in[6];
  const float* W1   = (const float*)d_in[7];
  const float* b1   = (const float*)d_in[8];
  const float* W2   = (const float*)d_in[9];
  const float* b2   = (const float*)d_in[10];
  float* out = (float*)d_out;

  const int N = in_sizes[0] / NDIM;   // 50000
  const int E = in_sizes[1];          // 800000
  const int Mp = (N + 127) & ~127;    // 50048
  const int nb = (N + SCB - 1) / SCB;

  char* ws = (char*)d_ws;
  size_t off = 0;
  auto alloc = [&](size_t bytes) -> char* {
    char* p = ws + off;
    off += (bytes + 255) & ~(size_t)255;
    return p;
  };
  unsigned short* xb   = (unsigned short*)alloc((size_t)Mp * NDIM * 2);
  unsigned short* Q    = (unsigned short*)alloc((size_t)Mp * NDIM * 2);
  unsigned short* Kb   = (unsigned short*)alloc((size_t)Mp * NDIM * 2);
  unsigned short* Vb   = (unsigned short*)alloc((size_t)Mp * NDIM * 2);
  unsigned short* wqkvt = (unsigned short*)alloc((size_t)768 * 256 * 2);
  unsigned short* wft   = (unsigned short*)alloc((size_t)256 * 512 * 2);
  unsigned short* w2t   = (unsigned short*)alloc((size_t)256 * 256 * 2);
  float*          bc    = (float*)alloc(256 * 4);
  int* deg8   = (int*)alloc((size_t)8 * N * 4);
  int* rbase  = (int*)alloc((size_t)8 * N * 4);
  int* offs   = (int*)alloc((size_t)(N + 1) * 4);
  unsigned short* erank = (unsigned short*)alloc((size_t)E * 2);
  int* ssrc   = (int*)alloc((size_t)E * 4);
  int* bsum   = (int*)alloc((size_t)nb * 4);

  unsigned char* K8 = (unsigned char*)Kb;
  unsigned char* V8 = (unsigned char*)Vb;
  unsigned short* agg = Q;    // attn writes in place over Q
  unsigned short* h1  = Kb;   // Kb dead after attn

  const int n8  = N * NDIM / 8;
  const int nbx = (n8 + 255) / 256;
  const int nbw = (393472 + 255) / 256;
  const int nsc = (E + 255) / 256;          // 3125
  const int mt  = Mp / 128;                 // 391

  hipMemsetAsync(deg8, 0, (size_t)8 * N * 4, stream);

  // prep: xconv + weight conversions
  prep_k<<<nbx + nbw, 256, 0, stream>>>(
      x, xb, n8, nbx, Wqkv, wqkvt, W1, wft, W2, w2t, Wout, bout, b1, bc);

  // FUSED: 8-replica histogram (atomic wall) overlapped with QKV GEMM
  histqkv_k<<<nsc + mt * 6, 256, 0, stream>>>(
      dst, deg8, erank, E, N, nsc,
      xb, wqkvt, bqkv, Q, K8, V8, N);

  // CSR scan + replica bases
  bsum_k<<<nb, SCB, 0, stream>>>(deg8, bsum, N);
  bscan_k<<<1, 128, 0, stream>>>(bsum, nb);
  offs_k<<<nb, SCB, 0, stream>>>(deg8, bsum, offs, rbase, N);

  // atomic-free scatter
  scatter2_k<<<nsc, 256, 0, stream>>>(src, dst, rbase, erank, ssrc, E, N);

  // edge-softmax aggregation (agg == Q in place)
  attn_k<<<(N + 3) / 4, 256, 0, stream>>>(Q, K8, V8, offs, ssrc, agg, N);

  // FUSED FFN-in: gelu(x@W1a + agg@(Wout@W1b) + bc) -> h1 (bf16)
  mgemm_k<2><<<mt * 2, 256, 0, stream>>>(
      xb, agg, wft, bc, nullptr, h1, N, 256, 512, 256, 512, 2);

  // h1 @ W2 + b2 -> out (fp32)
  mgemm_k<0><<<mt * 2, 256, 0, stream>>>(
      h1, nullptr, w2t, b2, out, nullptr, N, 256, 256, 256, 256, 2);
}